// Round 9
// baseline (468.661 us; speedup 1.0000x reference)
//
#include <hip/hip_runtime.h>
#include <stdint.h>

#define S_LEN 2048
#define D_MODEL 1024
#define N_HEAD 16
#define D_HEAD 64
#define N_BATCH 2
#define M_TOK (N_BATCH * S_LEN)  // 4096

typedef unsigned short u16;
typedef unsigned int u32;
typedef __attribute__((ext_vector_type(8))) short bf16x8;
typedef __attribute__((ext_vector_type(4))) short s16x4;
typedef __attribute__((ext_vector_type(4))) float f32x4;
typedef __attribute__((ext_vector_type(4))) unsigned short u16x4;

#define MFMA16(a, b, c) __builtin_amdgcn_mfma_f32_16x16x32_bf16((a), (b), (c), 0, 0, 0)

#if defined(__has_builtin)
#if __has_builtin(__builtin_amdgcn_mfma_f32_16x16x16bf16_1k)
#define HAVE_MFMA_16x16x16 1
#define MFMA_PV(a, b, c) __builtin_amdgcn_mfma_f32_16x16x16bf16_1k((a), (b), (c), 0, 0, 0)
#endif
#endif

#define WAITCNT(n) asm volatile("s_waitcnt vmcnt(" #n ")" ::: "memory")
#define BAR() __builtin_amdgcn_s_barrier()

__device__ __forceinline__ u16 f2bf(float f) {
  unsigned int u = __float_as_uint(f);
  u = (u + 0x7FFFu + ((u >> 16) & 1u)) >> 16;
  return (u16)u;
}

__device__ __forceinline__ void gload_lds16(const u16* g, u16* l) {
  __builtin_amdgcn_global_load_lds((const __attribute__((address_space(1))) void*)g,
                                   (__attribute__((address_space(3))) void*)l, 16, 0, 0);
}

// ---------------- fp32 -> bf16 convert, all 7 tensors in one launch ----------------
#define N4BIG (M_TOK * D_MODEL / 4)     // 1048576
#define N4W (D_MODEL * D_MODEL / 4)     // 262144
__global__ __launch_bounds__(256) void cvt7_kernel(
    const float* __restrict__ sk, const float* __restrict__ sv, const float* __restrict__ sq,
    const float* __restrict__ swq, const float* __restrict__ swk, const float* __restrict__ swv,
    const float* __restrict__ swo, u16* __restrict__ dk, u16* __restrict__ dv, u16* __restrict__ dq,
    u16* __restrict__ dwq, u16* __restrict__ dwk, u16* __restrict__ dwv, u16* __restrict__ dwo) {
  const float* s;
  u16* d;
  int n4;
  switch (blockIdx.y) {
    case 0: s = sk; d = dk; n4 = N4BIG; break;
    case 1: s = sv; d = dv; n4 = N4BIG; break;
    case 2: s = sq; d = dq; n4 = N4BIG; break;
    case 3: s = swq; d = dwq; n4 = N4W; break;
    case 4: s = swk; d = dwk; n4 = N4W; break;
    case 5: s = swv; d = dwv; n4 = N4W; break;
    default: s = swo; d = dwo; n4 = N4W; break;
  }
  int i = blockIdx.x * blockDim.x + threadIdx.x;
  int stride = gridDim.x * blockDim.x;
  for (; i < n4; i += stride) {
    float4 v = ((const float4*)s)[i];
    u16x4 o = {f2bf(v.x), f2bf(v.y), f2bf(v.z), f2bf(v.w)};
    ((u16x4*)d)[i] = o;
  }
}

// ---------------- mask bit-pack: int32[4096][2048] -> u64[4096][32] -----------------
__global__ __launch_bounds__(256) void pack_mask(const int* __restrict__ mask,
                                                 unsigned long long* __restrict__ packed) {
  int wid = (blockIdx.x * blockDim.x + threadIdx.x) >> 6;
  int lane = threadIdx.x & 63;
  int nw = (gridDim.x * blockDim.x) >> 6;
  const int NW64 = M_TOK * (S_LEN / 64);  // 131072
  for (int widx = wid; widx < NW64; widx += nw) {
    int m = mask[(size_t)widx * 64 + lane];
    unsigned long long bits = __ballot(m != 0);
    if (lane == 0) packed[widx] = bits;
  }
}

// ---------------- GEMM body: C[M,N] = A[M,K]@Bw[N,K]^T, +bias, *scale ----------------
// m97 structure. outmode: 0 = bf16 row-major, 1 = fp32 row-major, 2 = bf16 [b][h][dh][s]
__device__ __forceinline__ void gemm_body(const u16* __restrict__ A, const u16* __restrict__ Bw,
                                          const float* __restrict__ bias, void* __restrict__ Cout,
                                          float scale, int outmode) {
  __shared__ u16 As[128 * 32];
  __shared__ u16 Bs[128 * 32];
  const int K = D_MODEL, N = D_MODEL;
  int tid = threadIdx.x;
  int w = tid >> 6, lane = tid & 63, lg = lane >> 4, lr = lane & 15;
  int m0 = blockIdx.x * 128, n0 = blockIdx.y * 128;
  int wr = w >> 1, wc = w & 1;
  f32x4 acc[4][4] = {};
  int r0 = tid >> 2;
  int r1 = 64 + (tid >> 2);
  int kk0 = (tid & 3) * 8;
  for (int kb = 0; kb < K; kb += 32) {
    gload_lds16(A + (size_t)(m0 + r0) * K + kb + kk0, As + w * 512);
    gload_lds16(A + (size_t)(m0 + r1) * K + kb + kk0, As + 2048 + w * 512);
    gload_lds16(Bw + (size_t)(n0 + r0) * K + kb + kk0, Bs + w * 512);
    gload_lds16(Bw + (size_t)(n0 + r1) * K + kb + kk0, Bs + 2048 + w * 512);
    __syncthreads();
    bf16x8 af[4], bfr[4];
#pragma unroll
    for (int i = 0; i < 4; i++)
      af[i] = *(const bf16x8*)(As + (wr * 64 + i * 16 + lr) * 32 + lg * 8);
#pragma unroll
    for (int i = 0; i < 4; i++)
      bfr[i] = *(const bf16x8*)(Bs + (wc * 64 + i * 16 + lr) * 32 + lg * 8);
#pragma unroll
    for (int mi = 0; mi < 4; mi++)
#pragma unroll
      for (int ni = 0; ni < 4; ni++)
        acc[mi][ni] = MFMA16(af[mi], bfr[ni], acc[mi][ni]);
    __syncthreads();
  }
#pragma unroll
  for (int mi = 0; mi < 4; mi++)
#pragma unroll
    for (int ni = 0; ni < 4; ni++) {
      int col = n0 + wc * 64 + ni * 16 + lr;
      float bv = bias[col];
      if (outmode == 2) {
        int row0 = m0 + wr * 64 + mi * 16 + lg * 4;
        int bb = row0 >> 11, ss = row0 & (S_LEN - 1);
        u16x4 pk;
#pragma unroll
        for (int r = 0; r < 4; r++) pk[r] = f2bf((acc[mi][ni][r] + bv) * scale);
        *(u16x4*)((u16*)Cout + ((size_t)((bb * N_HEAD + (col >> 6)) * D_HEAD + (col & 63)) * S_LEN + ss)) = pk;
      } else {
#pragma unroll
        for (int r = 0; r < 4; r++) {
          int row = m0 + wr * 64 + mi * 16 + lg * 4 + r;
          float v = (acc[mi][ni][r] + bv) * scale;
          if (outmode == 1)
            ((float*)Cout)[(size_t)row * N + col] = v;
          else
            ((u16*)Cout)[(size_t)row * N + col] = f2bf(v);
        }
      }
    }
}

// Q scale folds 1/sqrt(64) * log2(e) so attention uses exp2 directly.
#define QSCALE 0.18033688011112042f

__global__ __launch_bounds__(256) void proj3_kernel(
    const u16* __restrict__ kbf, const u16* __restrict__ vbf, const u16* __restrict__ qbf,
    const u16* __restrict__ wkb, const u16* __restrict__ wvb, const u16* __restrict__ wqb,
    const float* __restrict__ bk, const float* __restrict__ bv, const float* __restrict__ bq,
    u16* __restrict__ kup, u16* __restrict__ vtg, u16* __restrict__ qup) {
  int z = blockIdx.z;
  if (z == 0)
    gemm_body(kbf, wkb, bk, kup, 1.0f, 0);
  else if (z == 1)
    gemm_body(vbf, wvb, bv, vtg, 1.0f, 2);
  else
    gemm_body(qbf, wqb, bq, qup, QSCALE, 0);
}

__global__ __launch_bounds__(256) void gemm_out_kernel(const u16* __restrict__ A,
                                                       const u16* __restrict__ Bw,
                                                       const float* __restrict__ bias,
                                                       float* __restrict__ C) {
  gemm_body(A, Bw, bias, C, 1.0f, 1);
}

// ---------------- fused attention: K-only LDS (quad-buf), V direct from global ------
// grid = 512 flat blocks (XCD-chunk swizzled), 512 threads = 8 waves. Wave w owns
// q-rows [q0+16w, +16), full k. K tile [128 k][64 dh] (16KB, 2 gloads) in a 4-deep
// rotating buffer -> ONE s_barrier per tile (stager at kt+2 and slowest reader at kt
// touch distinct buffers; s_barrier bounds skew <1 phase). V^T PV-fragments are read
// per-lane from global (L2-resident; natural layout matches the 16x16x16 B-frag), so
// V loads and attn stores float freely across tile boundaries.
__global__ __launch_bounds__(512, 4) void attn_kernel(
    const u16* __restrict__ Qup, const u16* __restrict__ Kup, const u16* __restrict__ Vt,
    const u32* __restrict__ mpack, float* __restrict__ attn_out, u16* __restrict__ ctx) {
  __shared__ u16 kbuf[4][128 * 64];  // 64 KB
#if !defined(HAVE_MFMA_16x16x16)
  __shared__ u16 pbuf[8][16 * 64];
#endif
  int tid = threadIdx.x;
  int w = tid >> 6, lane = tid & 63, lg = lane >> 4, lr = lane & 15;

  // XCD-chunked bijective swizzle (512 % 8 == 0)
  int fb = blockIdx.x;
  int logical = (fb & 7) * 64 + (fb >> 3);
  int qx = logical & 15;
  int h = (logical >> 4) & 15;
  int b = logical >> 8;
  int q0 = qx * 128;
  int q = q0 + w * 16 + lr;
  const float NEGV = -100000000.0f;

  bf16x8 qf0, qf1;
  {
    const u16* qrow = Qup + (size_t)(b * S_LEN + q) * D_MODEL + h * D_HEAD;
    qf0 = *(const bf16x8*)(qrow + lg * 8);
    qf1 = *(const bf16x8*)(qrow + 32 + lg * 8);
  }
  const u16* Kb = Kup + (size_t)(b * S_LEN) * D_MODEL + h * D_HEAD;
  const u16* Vb = Vt + (size_t)(b * N_HEAD + h) * D_HEAD * S_LEN;
  const u32* mrow = mpack + (size_t)(b * S_LEN + q) * (S_LEN / 32);
  float* attn_b = attn_out + ((size_t)(b * N_HEAD + h) * S_LEN + q) * S_LEN;

  // K staging: thread -> (row = tid>>3, chunk = (tid&7)^(row&7)); LDS dest linear.
  int krow = tid >> 3;
  int kchunk = (tid & 7) ^ (krow & 7);
  const u16* KgA = Kb + (size_t)krow * D_MODEL + kchunk * 8;
  const int sw = lr & 7;  // read-side swizzle key

#define STAGE_K(bn, ktn)                                                    \
  do {                                                                      \
    const u16* _s = KgA + (size_t)(ktn) * 128 * D_MODEL;                    \
    gload_lds16(_s, &kbuf[bn][0] + w * 512);                                \
    gload_lds16(_s + (size_t)64 * D_MODEL, &kbuf[bn][4096] + w * 512);      \
  } while (0)

  // ================= pass 0: row sums =================
  float lsA = 0.f, lsB = 0.f;

#define P0_BODY(BN, MM)                                                     \
  {                                                                         \
    const u16* kc = &kbuf[BN][0];                                           \
    _Pragma("unroll") for (int t = 0; t < 8; t++) {                         \
      const u16* kr = kc + (t * 16 + lr) * 64;                              \
      bf16x8 k0 = *(const bf16x8*)(kr + ((lg ^ sw) << 3));                  \
      bf16x8 k1 = *(const bf16x8*)(kr + (((lg + 4) ^ sw) << 3));            \
      f32x4 a = {0.f, 0.f, 0.f, 0.f};                                       \
      a = MFMA16(k0, qf0, a);                                               \
      a = MFMA16(k1, qf1, a);                                               \
      u32 wbits = (t >> 1) == 0 ? (MM).x                                    \
                : (t >> 1) == 1 ? (MM).y                                    \
                : (t >> 1) == 2 ? (MM).z : (MM).w;                          \
      _Pragma("unroll") for (int r = 0; r < 4; r++) {                       \
        int j = (t * 16 + lg * 4 + r) & 31;                                 \
        float s = ((wbits >> j) & 1u) ? NEGV : a[r];                        \
        if (r & 1) lsB += exp2f(s); else lsA += exp2f(s);                   \
      }                                                                     \
    }                                                                       \
  }

  uint4 mA, mB;
  mA = *(const uint4*)(mrow);
  STAGE_K(0, 0);
  STAGE_K(1, 1);
  // full iterations: kt = 0..13 (stages reach tile 15)
  for (int it = 0; it < 7; it++) {
    int kt = it * 2;
    mB = *(const uint4*)(mrow + (kt + 1) * 4);
    STAGE_K((kt + 2) & 3, kt + 2);
    WAITCNT(5);  // leave {stage kt+1 (2), mask kt+1 (1), stage kt+2 (2)}
    BAR();
    P0_BODY(kt & 3, mA);
    mA = *(const uint4*)(mrow + (kt + 2) * 4);
    STAGE_K((kt + 3) & 3, kt + 3);
    WAITCNT(5);
    BAR();
    P0_BODY((kt + 1) & 3, mB);
  }
  // kt = 14
  mB = *(const uint4*)(mrow + 15 * 4);
  WAITCNT(3);  // leave {stage 15 (2), mask 15 (1)}
  BAR();
  P0_BODY(2, mA);
  // kt = 15
  WAITCNT(0);
  BAR();
  P0_BODY(3, mB);

  float lsum = lsA + lsB;
  lsum += __shfl_xor(lsum, 16);
  lsum += __shfl_xor(lsum, 32);
  float il2 = lsum > 0.f ? -__log2f(lsum) : 0.f;  // fold 1/lsum into exponent

  BAR();  // pass seam (safety margin; quad-buffer analysis says not required)

  // ================= pass 1: write attn, PV accumulate =================
  f32x4 ctxacc[4] = {};

#if defined(HAVE_MFMA_16x16x16)
  // V^T natural-layout B-frag: lane reads 8B at (d*16+lr)*S + kt*128 + t*16 + lg*4.
#define P1_BODY(BN, MM, KT)                                                 \
  {                                                                         \
    const u16* kc = &kbuf[BN][0];                                           \
    const u16* vg = Vb + (size_t)(KT) * 128;                                \
    _Pragma("unroll") for (int t = 0; t < 8; t++) {                         \
      s16x4 vf0 = *(const s16x4*)(vg + (size_t)(0 * 16 + lr) * S_LEN + t * 16 + lg * 4); \
      s16x4 vf1 = *(const s16x4*)(vg + (size_t)(1 * 16 + lr) * S_LEN + t * 16 + lg * 4); \
      s16x4 vf2 = *(const s16x4*)(vg + (size_t)(2 * 16 + lr) * S_LEN + t * 16 + lg * 4); \
      s16x4 vf3 = *(const s16x4*)(vg + (size_t)(3 * 16 + lr) * S_LEN + t * 16 + lg * 4); \
      const u16* kr = kc + (t * 16 + lr) * 64;                              \
      bf16x8 k0 = *(const bf16x8*)(kr + ((lg ^ sw) << 3));                  \
      bf16x8 k1 = *(const bf16x8*)(kr + (((lg + 4) ^ sw) << 3));            \
      f32x4 a = {0.f, 0.f, 0.f, 0.f};                                       \
      a = MFMA16(k0, qf0, a);                                               \
      a = MFMA16(k1, qf1, a);                                               \
      u32 wbits = (t >> 1) == 0 ? (MM).x                                    \
                : (t >> 1) == 1 ? (MM).y                                    \
                : (t >> 1) == 2 ? (MM).z : (MM).w;                          \
      f32x4 p;                                                              \
      u16x4 pb;                                                             \
      _Pragma("unroll") for (int r = 0; r < 4; r++) {                       \
        int j = (t * 16 + lg * 4 + r) & 31;                                 \
        float s = ((wbits >> j) & 1u) ? NEGV : (a[r] + il2);                \
        float pv = exp2f(s);                                                \
        p[r] = pv;                                                          \
        pb[r] = f2bf(pv);                                                   \
      }                                                                     \
      *(f32x4*)(attn_b + (KT) * 128 + t * 16 + lg * 4) = p;                 \
      s16x4 ap = {(short)pb[0], (short)pb[1], (short)pb[2], (short)pb[3]};  \
      ctxacc[0] = MFMA_PV(ap, vf0, ctxacc[0]);                              \
      ctxacc[1] = MFMA_PV(ap, vf1, ctxacc[1]);                              \
      ctxacc[2] = MFMA_PV(ap, vf2, ctxacc[2]);                              \
      ctxacc[3] = MFMA_PV(ap, vf3, ctxacc[3]);                              \
    }                                                                       \
  }
#else
  // Fallback: P through pbuf, V^T b128 global B-frags for 16x16x32.
#define P1_BODY(BN, MM, KT)                                                 \
  {                                                                         \
    const u16* kc = &kbuf[BN][0];                                           \
    const u16* vg = Vb + (size_t)(KT) * 128;                                \
    u16* pw = &pbuf[w][0];                                                  \
    _Pragma("unroll") for (int h2 = 0; h2 < 2; h2++) {                      \
      _Pragma("unroll") for (int tt = 0; tt < 4; tt++) {                    \
        const int t = h2 * 4 + tt;                                          \
        const u16* kr = kc + (t * 16 + lr) * 64;                            \
        bf16x8 k0 = *(const bf16x8*)(kr + ((lg ^ sw) << 3));                \
        bf16x8 k1 = *(const bf16x8*)(kr + (((lg + 4) ^ sw) << 3));          \
        f32x4 a = {0.f, 0.f, 0.f, 0.f};                                     \
        a = MFMA16(k0, qf0, a);                                              \
        a = MFMA16(k1, qf1, a);                                              \
        u32 wbits = (t >> 1) == 0 ? (MM).x                                  \
                  : (t >> 1) == 1 ? (MM).y                                  \
                  : (t >> 1) == 2 ? (MM).z : (MM).w;                        \
        f32x4 p;                                                            \
        u16x4 pb;                                                           \
        _Pragma("unroll") for (int r = 0; r < 4; r++) {                     \
          int j = (t * 16 + lg * 4 + r) & 31;                               \
          float s = ((wbits >> j) & 1u) ? NEGV : (a[r] + il2);              \
          float pv = exp2f(s);                                              \
          p[r] = pv;                                                        \
          pb[r] = f2bf(pv);                                                 \
        }                                                                   \
        *(f32x4*)(attn_b + (KT) * 128 + t * 16 + lg * 4) = p;               \
        *(u16x4*)(pw + lr * 64 + (((tt * 2 + (lg >> 1)) ^ sw) << 3) +       \
                  ((lg & 1) << 2)) = pb;                                    \
      }                                                                     \
      bf16x8 pa0 = *(const bf16x8*)(pw + lr * 64 + ((lg ^ sw) << 3));       \
      bf16x8 pa1 = *(const bf16x8*)(pw + lr * 64 + (((lg + 4) ^ sw) << 3)); \
      _Pragma("unroll") for (int d = 0; d < 4; d++) {                       \
        const u16* vr = vg + (size_t)(d * 16 + lr) * S_LEN + h2 * 64;       \
        bf16x8 v0 = *(const bf16x8*)(vr + lg * 8);                          \
        bf16x8 v1 = *(const bf16x8*)(vr + 32 + lg * 8);                     \
        ctxacc[d] = MFMA16(pa0, v0, ctxacc[d]);                             \
        ctxacc[d] = MFMA16(pa1, v1, ctxacc[d]);                             \
      }                                                                     \
    }                                                                       \
  }
#endif

  mA = *(const uint4*)(mrow);
  STAGE_K(0, 0);
  STAGE_K(1, 1);
  for (int it = 0; it < 7; it++) {
    int kt = it * 2;
    mB = *(const uint4*)(mrow + (kt + 1) * 4);
    STAGE_K((kt + 2) & 3, kt + 2);
    WAITCNT(5);  // leave {stage kt+1 (2), mask kt+1 (1), stage kt+2 (2)}; drains stores
    BAR();
    P1_BODY(kt & 3, mA, kt);
    mA = *(const uint4*)(mrow + (kt + 2) * 4);
    STAGE_K((kt + 3) & 3, kt + 3);
    WAITCNT(5);
    BAR();
    P1_BODY((kt + 1) & 3, mB, kt + 1);
  }
  // kt = 14
  mB = *(const uint4*)(mrow + 15 * 4);
  WAITCNT(3);
  BAR();
  P1_BODY(2, mA, 14);
  // kt = 15
  WAITCNT(0);
  BAR();
  P1_BODY(3, mB, 15);

  // context out: [B,S,H,DH] == [M_TOK, D_MODEL] row-major
#pragma unroll
  for (int d = 0; d < 4; d++)
#pragma unroll
    for (int r = 0; r < 4; r++) {
      int sq = q0 + w * 16 + lg * 4 + r;
      ctx[(size_t)(b * S_LEN + sq) * D_MODEL + h * D_HEAD + d * 16 + lr] = f2bf(ctxacc[d][r]);
    }
#undef STAGE_K
#undef P0_BODY
#undef P1_BODY
}

// ---------------- workspace layout (u16 units) ----------------
#define O_KBF 0u          // bf16 key input; reused for packed mask after projections
#define O_VBF 4194304u
#define O_QBF 8388608u
#define O_WQ 12582912u
#define O_WK 13631488u
#define O_WV 14680064u
#define O_WO 15728640u
#define O_QUP 16777216u
#define O_KUP 20971520u
#define O_VUP 25165824u   // V head-transposed [b][h][dh][s]
#define O_CTX 29360128u
// total = 33554432 u16 = 64 MiB

extern "C" void kernel_launch(void* const* d_in, const int* in_sizes, int n_in,
                              void* d_out, int out_size, void* d_ws, size_t ws_size,
                              hipStream_t stream) {
  const float* key = (const float*)d_in[0];
  const float* value = (const float*)d_in[1];
  const float* query = (const float*)d_in[2];
  const int* mask = (const int*)d_in[3];
  const float* Wq = (const float*)d_in[4];
  const float* bq = (const float*)d_in[5];
  const float* Wk = (const float*)d_in[6];
  const float* bk = (const float*)d_in[7];
  const float* Wv = (const float*)d_in[8];
  const float* bv = (const float*)d_in[9];
  const float* Wo = (const float*)d_in[10];
  const float* bo = (const float*)d_in[11];

  u16* ws = (u16*)d_ws;
  u16* kbf = ws + O_KBF;
  u16* vbf = ws + O_VBF;
  u16* qbf = ws + O_QBF;
  u16* wqb = ws + O_WQ;
  u16* wkb = ws + O_WK;
  u16* wvb = ws + O_WV;
  u16* wob = ws + O_WO;
  u16* qup = ws + O_QUP;
  u16* kup = ws + O_KUP;
  u16* vtg = ws + O_VUP;
  u16* ctxb = ws + O_CTX;

  float* out = (float*)d_out;
  float* attn = out + (size_t)N_BATCH * S_LEN * D_MODEL;

  cvt7_kernel<<<dim3(512, 7), 256, 0, stream>>>(key, value, query, Wq, Wk, Wv, Wo, kbf, vbf, qbf,
                                                wqb, wkb, wvb, wob);
  proj3_kernel<<<dim3(32, 8, 3), 256, 0, stream>>>(kbf, vbf, qbf, wkb, wvb, wqb, bk, bv, bq, kup,
                                                   vtg, qup);
  pack_mask<<<1024, 256, 0, stream>>>(mask, (unsigned long long*)kbf);
  attn_kernel<<<512, 512, 0, stream>>>(qup, kup, vtg, (const u32*)kbf, attn, ctxb);
  gemm_out_kernel<<<dim3(32, 8), 256, 0, stream>>>(ctxb, wob, bo, out);
}

// Round 10
// 333.831 us; speedup vs baseline: 1.4039x; 1.4039x over previous
//
#include <hip/hip_runtime.h>
#include <stdint.h>

#define S_LEN 2048
#define D_MODEL 1024
#define N_HEAD 16
#define D_HEAD 64
#define N_BATCH 2
#define M_TOK (N_BATCH * S_LEN)  // 4096

typedef unsigned short u16;
typedef unsigned int u32;
typedef __attribute__((ext_vector_type(8))) short bf16x8;
typedef __attribute__((ext_vector_type(4))) short s16x4;
typedef __attribute__((ext_vector_type(4))) float f32x4;
typedef __attribute__((ext_vector_type(4))) unsigned short u16x4;

#define MFMA16(a, b, c) __builtin_amdgcn_mfma_f32_16x16x32_bf16((a), (b), (c), 0, 0, 0)

#if defined(__has_builtin)
#if __has_builtin(__builtin_amdgcn_mfma_f32_16x16x16bf16_1k)
#define HAVE_MFMA_16x16x16 1
#define MFMA_PV(a, b, c) __builtin_amdgcn_mfma_f32_16x16x16bf16_1k((a), (b), (c), 0, 0, 0)
#endif
#endif

#define WAITCNT(n) asm volatile("s_waitcnt vmcnt(" #n ")" ::: "memory")
#define BAR() __builtin_amdgcn_s_barrier()

__device__ __forceinline__ u16 f2bf(float f) {
  unsigned int u = __float_as_uint(f);
  u = (u + 0x7FFFu + ((u >> 16) & 1u)) >> 16;
  return (u16)u;
}

__device__ __forceinline__ void gload_lds16(const u16* g, u16* l) {
  __builtin_amdgcn_global_load_lds((const __attribute__((address_space(1))) void*)g,
                                   (__attribute__((address_space(3))) void*)l, 16, 0, 0);
}

// ---------------- fp32 -> bf16 convert, all 7 tensors in one launch ----------------
#define N4BIG (M_TOK * D_MODEL / 4)     // 1048576
#define N4W (D_MODEL * D_MODEL / 4)     // 262144
__global__ __launch_bounds__(256) void cvt7_kernel(
    const float* __restrict__ sk, const float* __restrict__ sv, const float* __restrict__ sq,
    const float* __restrict__ swq, const float* __restrict__ swk, const float* __restrict__ swv,
    const float* __restrict__ swo, u16* __restrict__ dk, u16* __restrict__ dv, u16* __restrict__ dq,
    u16* __restrict__ dwq, u16* __restrict__ dwk, u16* __restrict__ dwv, u16* __restrict__ dwo) {
  const float* s;
  u16* d;
  int n4;
  switch (blockIdx.y) {
    case 0: s = sk; d = dk; n4 = N4BIG; break;
    case 1: s = sv; d = dv; n4 = N4BIG; break;
    case 2: s = sq; d = dq; n4 = N4BIG; break;
    case 3: s = swq; d = dwq; n4 = N4W; break;
    case 4: s = swk; d = dwk; n4 = N4W; break;
    case 5: s = swv; d = dwv; n4 = N4W; break;
    default: s = swo; d = dwo; n4 = N4W; break;
  }
  int i = blockIdx.x * blockDim.x + threadIdx.x;
  int stride = gridDim.x * blockDim.x;
  for (; i < n4; i += stride) {
    float4 v = ((const float4*)s)[i];
    u16x4 o = {f2bf(v.x), f2bf(v.y), f2bf(v.z), f2bf(v.w)};
    ((u16x4*)d)[i] = o;
  }
}

// ---------------- mask bit-pack: int32[4096][2048] -> u64[4096][32] -----------------
__global__ __launch_bounds__(256) void pack_mask(const int* __restrict__ mask,
                                                 unsigned long long* __restrict__ packed) {
  int wid = (blockIdx.x * blockDim.x + threadIdx.x) >> 6;
  int lane = threadIdx.x & 63;
  int nw = (gridDim.x * blockDim.x) >> 6;
  const int NW64 = M_TOK * (S_LEN / 64);  // 131072
  for (int widx = wid; widx < NW64; widx += nw) {
    int m = mask[(size_t)widx * 64 + lane];
    unsigned long long bits = __ballot(m != 0);
    if (lane == 0) packed[widx] = bits;
  }
}

// ---------------- GEMM body: C[M,N] = A[M,K]@Bw[N,K]^T, +bias, *scale ----------------
__device__ __forceinline__ void gemm_body(const u16* __restrict__ A, const u16* __restrict__ Bw,
                                          const float* __restrict__ bias, void* __restrict__ Cout,
                                          float scale, int outmode) {
  __shared__ u16 As[128 * 32];
  __shared__ u16 Bs[128 * 32];
  const int K = D_MODEL, N = D_MODEL;
  int tid = threadIdx.x;
  int w = tid >> 6, lane = tid & 63, lg = lane >> 4, lr = lane & 15;
  int m0 = blockIdx.x * 128, n0 = blockIdx.y * 128;
  int wr = w >> 1, wc = w & 1;
  f32x4 acc[4][4] = {};
  int r0 = tid >> 2;
  int r1 = 64 + (tid >> 2);
  int kk0 = (tid & 3) * 8;
  for (int kb = 0; kb < K; kb += 32) {
    gload_lds16(A + (size_t)(m0 + r0) * K + kb + kk0, As + w * 512);
    gload_lds16(A + (size_t)(m0 + r1) * K + kb + kk0, As + 2048 + w * 512);
    gload_lds16(Bw + (size_t)(n0 + r0) * K + kb + kk0, Bs + w * 512);
    gload_lds16(Bw + (size_t)(n0 + r1) * K + kb + kk0, Bs + 2048 + w * 512);
    __syncthreads();
    bf16x8 af[4], bfr[4];
#pragma unroll
    for (int i = 0; i < 4; i++)
      af[i] = *(const bf16x8*)(As + (wr * 64 + i * 16 + lr) * 32 + lg * 8);
#pragma unroll
    for (int i = 0; i < 4; i++)
      bfr[i] = *(const bf16x8*)(Bs + (wc * 64 + i * 16 + lr) * 32 + lg * 8);
#pragma unroll
    for (int mi = 0; mi < 4; mi++)
#pragma unroll
      for (int ni = 0; ni < 4; ni++)
        acc[mi][ni] = MFMA16(af[mi], bfr[ni], acc[mi][ni]);
    __syncthreads();
  }
#pragma unroll
  for (int mi = 0; mi < 4; mi++)
#pragma unroll
    for (int ni = 0; ni < 4; ni++) {
      int col = n0 + wc * 64 + ni * 16 + lr;
      float bv = bias[col];
      if (outmode == 2) {
        int row0 = m0 + wr * 64 + mi * 16 + lg * 4;
        int bb = row0 >> 11, ss = row0 & (S_LEN - 1);
        u16x4 pk;
#pragma unroll
        for (int r = 0; r < 4; r++) pk[r] = f2bf((acc[mi][ni][r] + bv) * scale);
        *(u16x4*)((u16*)Cout + ((size_t)((bb * N_HEAD + (col >> 6)) * D_HEAD + (col & 63)) * S_LEN + ss)) = pk;
      } else {
#pragma unroll
        for (int r = 0; r < 4; r++) {
          int row = m0 + wr * 64 + mi * 16 + lg * 4 + r;
          float v = (acc[mi][ni][r] + bv) * scale;
          if (outmode == 1)
            ((float*)Cout)[(size_t)row * N + col] = v;
          else
            ((u16*)Cout)[(size_t)row * N + col] = f2bf(v);
        }
      }
    }
}

// Q scale folds 1/sqrt(64) * log2(e) so attention uses exp2 directly.
#define QSCALE 0.18033688011112042f

__global__ __launch_bounds__(256) void proj3_kernel(
    const u16* __restrict__ kbf, const u16* __restrict__ vbf, const u16* __restrict__ qbf,
    const u16* __restrict__ wkb, const u16* __restrict__ wvb, const u16* __restrict__ wqb,
    const float* __restrict__ bk, const float* __restrict__ bv, const float* __restrict__ bq,
    u16* __restrict__ kup, u16* __restrict__ vtg, u16* __restrict__ qup) {
  int z = blockIdx.z;
  if (z == 0)
    gemm_body(kbf, wkb, bk, kup, 1.0f, 0);
  else if (z == 1)
    gemm_body(vbf, wvb, bv, vtg, 1.0f, 2);
  else
    gemm_body(qbf, wqb, bq, qup, QSCALE, 0);
}

__global__ __launch_bounds__(256) void gemm_out_kernel(const u16* __restrict__ A,
                                                       const u16* __restrict__ Bw,
                                                       const float* __restrict__ bias,
                                                       float* __restrict__ C) {
  gemm_body(A, Bw, bias, C, 1.0f, 1);
}

// ---------------- attention pass 0: partial row sums, k-split x2 --------------------
// grid = 2048 flat (XCD swizzled): (b, h, qb 0..31, khalf). 256 thr = 4 waves; wave w
// owns q-rows [qb*64 + 16w, +16) over k in [khalf*1024, +1024) (16 tiles of 64).
// K dbuf 16KB -> 8 blocks/CU = 32 waves (100% occ). Writes lsum_half to workspace.
__global__ __launch_bounds__(256, 8) void attn_p0(const u16* __restrict__ Qup,
                                                  const u16* __restrict__ Kup,
                                                  const u32* __restrict__ mpack,
                                                  float* __restrict__ lsums) {
  __shared__ u16 kbuf[2][64 * 64];
  int tid = threadIdx.x;
  int w = tid >> 6, lane = tid & 63, lg = lane >> 4, lr = lane & 15;
  int fb = blockIdx.x;
  int logical = (fb & 7) * 256 + (fb >> 3);
  int khalf = logical & 1;
  int qb = (logical >> 1) & 31;
  int h = (logical >> 6) & 15;
  int b = logical >> 10;
  int q0 = qb * 64;
  int q = q0 + w * 16 + lr;
  const float NEGV = -100000000.0f;

  bf16x8 qf0, qf1;
  {
    const u16* qrow = Qup + (size_t)(b * S_LEN + q) * D_MODEL + h * D_HEAD;
    qf0 = *(const bf16x8*)(qrow + lg * 8);
    qf1 = *(const bf16x8*)(qrow + 32 + lg * 8);
  }
  const u16* Kb = Kup + (size_t)(b * S_LEN) * D_MODEL + h * D_HEAD;
  const u32* mrow = mpack + (size_t)(b * S_LEN + q) * (S_LEN / 32) + khalf * 32;

  // staging: 256 thr, tile 8KB -> 2 gloads; thread -> (row=tid>>3, chunk^(row&7))
  int srow = tid >> 3;  // 0..31; second gload +32 (same &7)
  int schunk = (tid & 7) ^ (srow & 7);
  const u16* KgA = Kb + (size_t)(khalf * 1024 + srow) * D_MODEL + schunk * 8;
  const int sw = lr & 7;

#define STAGE_K0(bn, ktn)                                                   \
  do {                                                                      \
    const u16* _s = KgA + (size_t)(ktn) * 64 * D_MODEL;                     \
    gload_lds16(_s, &kbuf[bn][0] + w * 512);                                \
    gload_lds16(_s + (size_t)32 * D_MODEL, &kbuf[bn][2048] + w * 512);      \
  } while (0)

  float lsA = 0.f, lsB = 0.f;
#define P0_BODY(BN, MM)                                                     \
  {                                                                         \
    const u16* kc = &kbuf[BN][0];                                           \
    _Pragma("unroll") for (int t = 0; t < 4; t++) {                         \
      const u16* kr = kc + (t * 16 + lr) * 64;                              \
      bf16x8 k0 = *(const bf16x8*)(kr + ((lg ^ sw) << 3));                  \
      bf16x8 k1 = *(const bf16x8*)(kr + (((lg + 4) ^ sw) << 3));            \
      f32x4 a = {0.f, 0.f, 0.f, 0.f};                                       \
      a = MFMA16(k0, qf0, a);                                               \
      a = MFMA16(k1, qf1, a);                                               \
      u32 wbits = (t < 2) ? (MM).x : (MM).y;                                \
      _Pragma("unroll") for (int r = 0; r < 4; r++) {                       \
        int j = (t * 16 + lg * 4 + r) & 31;                                 \
        float s = ((wbits >> j) & 1u) ? NEGV : a[r];                        \
        if (r & 1) lsB += exp2f(s); else lsA += exp2f(s);                   \
      }                                                                     \
    }                                                                       \
  }

  uint2 mA, mB;
  mA = *(const uint2*)(mrow);
  STAGE_K0(0, 0);
  for (int it = 0; it < 7; it++) {
    int kt = it * 2;
    mB = *(const uint2*)(mrow + (kt + 1) * 2);
    STAGE_K0(1, kt + 1);
    WAITCNT(3);
    BAR();
    P0_BODY(0, mA);
    BAR();
    mA = *(const uint2*)(mrow + (kt + 2) * 2);
    STAGE_K0(0, kt + 2);
    WAITCNT(3);
    BAR();
    P0_BODY(1, mB);
    BAR();
  }
  mB = *(const uint2*)(mrow + 15 * 2);
  STAGE_K0(1, 15);
  WAITCNT(3);
  BAR();
  P0_BODY(0, mA);
  BAR();
  WAITCNT(0);
  BAR();
  P0_BODY(1, mB);

  float lsum = lsA + lsB;
  lsum += __shfl_xor(lsum, 16);
  lsum += __shfl_xor(lsum, 32);
  if (lg == 0) lsums[(size_t)khalf * 65536 + (size_t)(b * N_HEAD + h) * S_LEN + q] = lsum;
#undef STAGE_K0
#undef P0_BODY
}

// ---------------- attention pass 1: attn write (256B segments) + PV -----------------
// grid = 512 flat (XCD swizzled), 512 thr = 8 waves; wave w: q-rows [q0+16w,+16),
// full k, KVBLK=64 (32 tiles). K + V^T dbuf in LDS (r8 structure). Per tile: P f32
// goes through padded LDS [16][68] and is stored cooperatively with 16 consecutive
// lanes per row -> 256B contiguous segments (vs 64B from the raw fragment layout).
__global__ __launch_bounds__(512, 4) void attn_p1(
    const u16* __restrict__ Qup, const u16* __restrict__ Kup, const u16* __restrict__ Vt,
    const u32* __restrict__ mpack, const float* __restrict__ lsums,
    float* __restrict__ attn_out, u16* __restrict__ ctx) {
  __shared__ u16 kbuf[2][64 * 64];       // 16 KB
  __shared__ u16 vbuf[2][64 * 64];       // 16 KB
  __shared__ float pbuf[8][16][68];      // 34 KB, padded for bank spread
  int tid = threadIdx.x;
  int w = tid >> 6, lane = tid & 63, lg = lane >> 4, lr = lane & 15;
  int fb = blockIdx.x;
  int logical = (fb & 7) * 64 + (fb >> 3);
  int qx = logical & 15;
  int h = (logical >> 4) & 15;
  int b = logical >> 8;
  int q0 = qx * 128;
  int q = q0 + w * 16 + lr;
  const float NEGV = -100000000.0f;

  bf16x8 qf0, qf1;
  {
    const u16* qrow = Qup + (size_t)(b * S_LEN + q) * D_MODEL + h * D_HEAD;
    qf0 = *(const bf16x8*)(qrow + lg * 8);
    qf1 = *(const bf16x8*)(qrow + 32 + lg * 8);
  }
  const u16* Kb = Kup + (size_t)(b * S_LEN) * D_MODEL + h * D_HEAD;
  const u16* Vb = Vt + (size_t)(b * N_HEAD + h) * D_HEAD * S_LEN;
  const u32* mrow = mpack + (size_t)(b * S_LEN + q) * (S_LEN / 32);
  // per-wave attn row base (rows q0+16w .. +15)
  float* attn_w = attn_out + ((size_t)(b * N_HEAD + h) * S_LEN + q0 + w * 16) * S_LEN;

  // il2 = -log2(lsum0 + lsum1) for this lane's q-row
  float il2;
  {
    size_t idx = (size_t)(b * N_HEAD + h) * S_LEN + q;
    float tot = lsums[idx] + lsums[65536 + idx];
    il2 = tot > 0.f ? -__log2f(tot) : 0.f;
  }

  // staging: 512 thr, tile 8KB -> 1 gload; thread -> (row=tid>>3, chunk^(row&7))
  int srow = tid >> 3;  // 0..63
  int schunk = (tid & 7) ^ (srow & 7);
  const u16* KgA = Kb + (size_t)srow * D_MODEL + schunk * 8;
  const u16* VgA = Vb + (size_t)srow * S_LEN + schunk * 8;
  const int sw = lr & 7;

#define SK(bn, ktn) gload_lds16(KgA + (size_t)(ktn) * 64 * D_MODEL, &kbuf[bn][w * 512])
#define SV(bn, ktn) gload_lds16(VgA + (size_t)(ktn) * 64, &vbuf[bn][w * 512])

  f32x4 ctxacc[4] = {};

#if defined(HAVE_MFMA_16x16x16)
#define PV_STEP(vc, t)                                                      \
  {                                                                         \
    s16x4 ap = {(short)pb[0], (short)pb[1], (short)pb[2], (short)pb[3]};    \
    _Pragma("unroll") for (int d = 0; d < 4; d++) {                         \
      s16x4 vf = *(const s16x4*)((vc) + (d * 16 + lr) * 64 +                \
                                 ((((t)*2 + (lg >> 1)) ^ sw) << 3) +        \
                                 ((lg & 1) << 2));                          \
      ctxacc[d] = MFMA_PV(ap, vf, ctxacc[d]);                               \
    }                                                                       \
  }
#else
#define PV_STEP(vc, t) (void)pb;
#endif

#define P1_BODY(BN, MM, KT)                                                 \
  {                                                                         \
    const u16* kc = &kbuf[BN][0];                                           \
    const u16* vc = &vbuf[BN][0];                                           \
    float* pw = &pbuf[w][0][0];                                             \
    _Pragma("unroll") for (int t = 0; t < 4; t++) {                         \
      const u16* kr = kc + (t * 16 + lr) * 64;                              \
      bf16x8 k0 = *(const bf16x8*)(kr + ((lg ^ sw) << 3));                  \
      bf16x8 k1 = *(const bf16x8*)(kr + (((lg + 4) ^ sw) << 3));            \
      f32x4 a = {0.f, 0.f, 0.f, 0.f};                                       \
      a = MFMA16(k0, qf0, a);                                               \
      a = MFMA16(k1, qf1, a);                                               \
      u32 wbits = (t < 2) ? (MM).x : (MM).y;                                \
      f32x4 p;                                                              \
      u16x4 pb;                                                             \
      _Pragma("unroll") for (int r = 0; r < 4; r++) {                       \
        int j = (t * 16 + lg * 4 + r) & 31;                                 \
        float s = ((wbits >> j) & 1u) ? NEGV : (a[r] + il2);                \
        float pv = exp2f(s);                                                \
        p[r] = pv;                                                          \
        pb[r] = f2bf(pv);                                                   \
      }                                                                     \
      *(f32x4*)(pw + lr * 68 + t * 16 + lg * 4) = p;                        \
      PV_STEP(vc, t)                                                        \
    }                                                                       \
    /* fallback PV: read P back as f32, convert, 16x16x32 */                \
    P1_FALLBACK_PV(vc)                                                      \
    /* cooperative attn store: 4 rows x 256B per instr, 4 instrs */         \
    _Pragma("unroll") for (int i = 0; i < 4; i++) {                         \
      int rl = (lane >> 4) + i * 4;                                         \
      int cc = lane & 15;                                                   \
      f32x4 v = *(const f32x4*)(&pbuf[w][0][0] + rl * 68 + cc * 4);         \
      *(f32x4*)(attn_w + (size_t)rl * S_LEN + (KT) * 64 + cc * 4) = v;      \
    }                                                                       \
  }

#if defined(HAVE_MFMA_16x16x16)
#define P1_FALLBACK_PV(vc)
#else
#define P1_FALLBACK_PV(vc)                                                  \
  {                                                                         \
    float* pw = &pbuf[w][0][0];                                             \
    bf16x8 pa0, pa1;                                                        \
    _Pragma("unroll") for (int e = 0; e < 8; e++) {                         \
      pa0[e] = (short)f2bf(pw[lr * 68 + lg * 8 + e]);                       \
      pa1[e] = (short)f2bf(pw[lr * 68 + 32 + lg * 8 + e]);                  \
    }                                                                       \
    _Pragma("unroll") for (int d = 0; d < 4; d++) {                         \
      const u16* vr = (vc) + (d * 16 + lr) * 64;                            \
      bf16x8 v0 = *(const bf16x8*)(vr + ((lg ^ sw) << 3));                  \
      bf16x8 v1 = *(const bf16x8*)(vr + (((lg + 4) ^ sw) << 3));            \
      ctxacc[d] = MFMA16(pa0, v0, ctxacc[d]);                               \
      ctxacc[d] = MFMA16(pa1, v1, ctxacc[d]);                               \
    }                                                                       \
  }
#endif

  uint2 mA, mB;
  mA = *(const uint2*)(mrow);
  SK(0, 0);
  SV(0, 0);
  // peeled first double-iteration (first wait = 3, then steady 7)
  mB = *(const uint2*)(mrow + 1 * 2);
  SK(1, 1);
  SV(1, 1);
  WAITCNT(3);
  BAR();
  P1_BODY(0, mA, 0);
  BAR();
  mA = *(const uint2*)(mrow + 2 * 2);
  SK(0, 2);
  SV(0, 2);
  WAITCNT(7);
  BAR();
  P1_BODY(1, mB, 1);
  BAR();
  for (int it = 1; it < 15; it++) {
    int kt = it * 2;
    mB = *(const uint2*)(mrow + (kt + 1) * 2);
    SK(1, kt + 1);
    SV(1, kt + 1);
    WAITCNT(7);  // leaves {4 stores prev body, mask+K+V next} -> current tile ready
    BAR();
    P1_BODY(0, mA, kt);
    BAR();
    mA = *(const uint2*)(mrow + (kt + 2) * 2);
    SK(0, kt + 2);
    SV(0, kt + 2);
    WAITCNT(7);
    BAR();
    P1_BODY(1, mB, kt + 1);
    BAR();
  }
  // tile 30 (stages tile 31)
  mB = *(const uint2*)(mrow + 31 * 2);
  SK(1, 31);
  SV(1, 31);
  WAITCNT(7);
  BAR();
  P1_BODY(0, mA, 30);
  BAR();
  // tile 31
  WAITCNT(4);  // drain stage 31; leave the 4 stores of tile 30
  BAR();
  P1_BODY(1, mB, 31);

  // context out: [B,S,H,DH] == [M_TOK, D_MODEL] row-major
#pragma unroll
  for (int d = 0; d < 4; d++)
#pragma unroll
    for (int r = 0; r < 4; r++) {
      int sq = q0 + w * 16 + lg * 4 + r;
      ctx[(size_t)(b * S_LEN + sq) * D_MODEL + h * D_HEAD + d * 16 + lr] = f2bf(ctxacc[d][r]);
    }
#undef SK
#undef SV
#undef P1_BODY
#undef PV_STEP
#undef P1_FALLBACK_PV
}

// ---------------- workspace layout (u16 units) ----------------
#define O_KBF 0u          // bf16 key input; reused for packed mask after projections
#define O_VBF 4194304u    // bf16 value input; reused for lsums (f32[2][65536]) after proj
#define O_QBF 8388608u
#define O_WQ 12582912u
#define O_WK 13631488u
#define O_WV 14680064u
#define O_WO 15728640u
#define O_QUP 16777216u
#define O_KUP 20971520u
#define O_VUP 25165824u   // V head-transposed [b][h][dh][s]
#define O_CTX 29360128u
// total = 33554432 u16 = 64 MiB

extern "C" void kernel_launch(void* const* d_in, const int* in_sizes, int n_in,
                              void* d_out, int out_size, void* d_ws, size_t ws_size,
                              hipStream_t stream) {
  const float* key = (const float*)d_in[0];
  const float* value = (const float*)d_in[1];
  const float* query = (const float*)d_in[2];
  const int* mask = (const int*)d_in[3];
  const float* Wq = (const float*)d_in[4];
  const float* bq = (const float*)d_in[5];
  const float* Wk = (const float*)d_in[6];
  const float* bk = (const float*)d_in[7];
  const float* Wv = (const float*)d_in[8];
  const float* bv = (const float*)d_in[9];
  const float* Wo = (const float*)d_in[10];
  const float* bo = (const float*)d_in[11];

  u16* ws = (u16*)d_ws;
  u16* kbf = ws + O_KBF;
  u16* vbf = ws + O_VBF;
  u16* qbf = ws + O_QBF;
  u16* wqb = ws + O_WQ;
  u16* wkb = ws + O_WK;
  u16* wvb = ws + O_WV;
  u16* wob = ws + O_WO;
  u16* qup = ws + O_QUP;
  u16* kup = ws + O_KUP;
  u16* vtg = ws + O_VUP;
  u16* ctxb = ws + O_CTX;
  float* lsums = (float*)(ws + O_VBF);  // dead vbf region after projections

  float* out = (float*)d_out;
  float* attn = out + (size_t)N_BATCH * S_LEN * D_MODEL;

  cvt7_kernel<<<dim3(512, 7), 256, 0, stream>>>(key, value, query, Wq, Wk, Wv, Wo, kbf, vbf, qbf,
                                                wqb, wkb, wvb, wob);
  proj3_kernel<<<dim3(32, 8, 3), 256, 0, stream>>>(kbf, vbf, qbf, wkb, wvb, wqb, bk, bv, bq, kup,
                                                   vtg, qup);
  pack_mask<<<1024, 256, 0, stream>>>(mask, (unsigned long long*)kbf);
  attn_p0<<<2048, 256, 0, stream>>>(qup, kup, (const u32*)kbf, lsums);
  attn_p1<<<512, 512, 0, stream>>>(qup, kup, vtg, (const u32*)kbf, lsums, attn, ctxb);
  gemm_out_kernel<<<dim3(32, 8), 256, 0, stream>>>(ctxb, wob, bo, out);
}